// Round 1
// 409.165 us; speedup vs baseline: 1.1784x; 1.1784x over previous
//
#include <hip/hip_runtime.h>

typedef int v4i __attribute__((ext_vector_type(4)));

#define BM 256
#define BN 256
#define BKB 64   // K-bytes per ring slot (i8 elems). 64 B rows, same swizzle geometry as before.
#define NRING 4  // 4 slots x (16KB A + 16KB B) = 128 KB LDS, prefetch distance 3

// async global->LDS, 16B per lane. LDS dest = wave-uniform base + lane*16.
#define GLOAD_LDS(gptr, lptr)                                                         \
  __builtin_amdgcn_global_load_lds(                                                   \
      (const __attribute__((address_space(1))) unsigned int*)(gptr),                  \
      (__attribute__((address_space(3))) unsigned int*)(lptr), 16, 0, 0)

// ---------- preprocessing ----------

// One dispatch: blocks [0, grid-2] reduce max|W|, last block reduces max|b|.
__global__ void absmax2_kernel(const float4* __restrict__ W4, long nW4,
                               const float4* __restrict__ b4, int nb4,
                               unsigned* __restrict__ mx) {
  __shared__ float sm[4];
  float m = 0.f;
  const bool isB = (blockIdx.x == gridDim.x - 1);
  if (!isB) {
    const long stride = (long)(gridDim.x - 1) * blockDim.x;
    for (long i = blockIdx.x * (long)blockDim.x + threadIdx.x; i < nW4; i += stride) {
      float4 v = W4[i];
      m = fmaxf(m, fmaxf(fmaxf(fabsf(v.x), fabsf(v.y)), fmaxf(fabsf(v.z), fabsf(v.w))));
    }
  } else {
    for (int i = threadIdx.x; i < nb4; i += blockDim.x) {
      float4 v = b4[i];
      m = fmaxf(m, fmaxf(fmaxf(fabsf(v.x), fabsf(v.y)), fmaxf(fabsf(v.z), fabsf(v.w))));
    }
  }
  for (int off = 32; off > 0; off >>= 1)
    m = fmaxf(m, __shfl_down(m, off));
  if ((threadIdx.x & 63) == 0) sm[threadIdx.x >> 6] = m;
  __syncthreads();
  if (threadIdx.x == 0) {
    m = fmaxf(fmaxf(sm[0], sm[1]), fmaxf(sm[2], sm[3]));
    atomicMax(mx + (isB ? 1 : 0), __float_as_uint(m));  // nonneg: uint order == float order
  }
}

// Per-row int8 quantization of x: one block per row (K=4096, 256 threads x 16 vals).
// Lane-contiguous float4 loads (1KB/wave-instr) + packed-dword stores (coalesced).
__global__ void xquant_kernel(const float4* __restrict__ X4,
                              signed char* __restrict__ Q,
                              float* __restrict__ sx, int K) {
  __shared__ float sm[4];
  const int row = blockIdx.x;
  const int tid = threadIdx.x;
  const float4* xr = X4 + (size_t)row * (K / 4);
  float4 v[4];  // assumes K == 4096: 256 threads * 4 float4 = 1024 float4
  float m = 0.f;
#pragma unroll
  for (int i = 0; i < 4; ++i) {
    v[i] = xr[tid + i * 256];
    m = fmaxf(m, fmaxf(fmaxf(fabsf(v[i].x), fabsf(v[i].y)),
                       fmaxf(fabsf(v[i].z), fabsf(v[i].w))));
  }
  for (int off = 32; off > 0; off >>= 1) m = fmaxf(m, __shfl_down(m, off));
  if ((tid & 63) == 0) sm[tid >> 6] = m;
  __syncthreads();
  const float total = fmaxf(fmaxf(sm[0], sm[1]), fmaxf(sm[2], sm[3]));
  const float inv = 127.f / total;
  int* qw = (int*)(Q + (size_t)row * K);
#pragma unroll
  for (int i = 0; i < 4; ++i) {
    const float* f = (const float*)&v[i];
    int b[4];
#pragma unroll
    for (int j = 0; j < 4; ++j) {
      float r = rintf(f[j] * inv);
      r = fmaxf(-127.f, fminf(127.f, r));
      b[j] = ((int)r) & 255;
    }
    qw[tid + i * 256] = b[0] | (b[1] << 8) | (b[2] << 16) | (b[3] << 24);
  }
  if (tid == 0) sx[row] = total * (1.f / 127.f);
}

// Fused: ternarize W -> i8{-1,0,1}, one float4 -> one packed dword per iter (coalesced).
// Last block ternarizes b -> fp32.
__global__ void prep_w_kernel(const float4* __restrict__ W4, long nW4,
                              const float4* __restrict__ b4, int nb4,
                              const unsigned* __restrict__ mx,
                              const float* __restrict__ bscale,
                              int* __restrict__ Twi, float4* __restrict__ bt) {
  if (blockIdx.x == gridDim.x - 1) {  // bias block
    const float delta = 0.05f * __uint_as_float(mx[1]);
    const float s = *bscale;
    for (int i = threadIdx.x; i < nb4; i += blockDim.x) {
      float4 v = b4[i];
      float4 o;
      o.x = v.x > delta ? s : (v.x < -delta ? -s : 0.f);
      o.y = v.y > delta ? s : (v.y < -delta ? -s : 0.f);
      o.z = v.z > delta ? s : (v.z < -delta ? -s : 0.f);
      o.w = v.w > delta ? s : (v.w < -delta ? -s : 0.f);
      bt[i] = o;
    }
    return;
  }
  const float delta = 0.05f * __uint_as_float(mx[0]);
  const long stride = (long)(gridDim.x - 1) * blockDim.x;
  for (long i = blockIdx.x * (long)blockDim.x + threadIdx.x; i < nW4; i += stride) {
    float4 w = W4[i];
    int b0 = w.x > delta ? 1 : (w.x < -delta ? 0xFF : 0);
    int b1 = w.y > delta ? 1 : (w.y < -delta ? 0xFF : 0);
    int b2 = w.z > delta ? 1 : (w.z < -delta ? 0xFF : 0);
    int b3 = w.w > delta ? 1 : (w.w < -delta ? 0xFF : 0);
    Twi[i] = b0 | (b1 << 8) | (b2 << 16) | (b3 << 24);
  }
}

// ---------- GEMM: C[m,n] = ws*sx[m]*(sum_k Aq[m,k]*T[n,k]) + bt[n], exact i32 acc ----
// 256x256 tile, 8 waves (2Mx4N), each wave 128x64 via 8x4 grid of 16x16x64 i8 MFMAs.
// Ring of 4 LDS slots (128 KB), prefetch distance 3, counted vmcnt(8) -- loads for
// tiles t+2,t+3 stay in flight across the barrier (never drain to 0 in the loop).
// Same XOR chunk swizzle + fragment layout as the verified 128^2 version:
//   stage:  idx -> row=idx>>2, global chunk=(idx&3)^((idx>>3)&3), linear LDS dest
//   read :  kchunk = quad ^ ((l16>>1)&3)  (involution matches stage side)
// Race-freedom: STAGE((t+3)&3) rewrites the slot read at tile t-1; all its ds_reads
// completed before the end-of-(t-1) barrier (lgkmcnt before MFMA), and the stage is
// issued only after that barrier. vmcnt(8) + in-order VMEM retirement guarantees
// tile t+1 is fully in LDS before the barrier that opens it.
__global__ __launch_bounds__(512, 2) void gemm_tern_i8(
    const signed char* __restrict__ A,   // [M,K] i8 quantized x
    const signed char* __restrict__ B,   // [N,K] i8 ternary {-1,0,1}
    const float* __restrict__ sx,        // [M] per-row x scale
    const float* __restrict__ bt,        // [N]
    const float* __restrict__ wsc,       // scalar
    float* __restrict__ C,               // [M,N] fp32
    int M, int N, int K) {
  __shared__ __align__(16) signed char lds[NRING][2][BM * BKB];  // 4*2*16KB = 128 KB

  const int tid = threadIdx.x;
  const int wave = tid >> 6;
  const int lane = tid & 63;
  const int wm = wave >> 2, wn = wave & 3;  // 2 x 4 wave grid
  const int quad = lane >> 4;               // 0..3
  const int l16 = lane & 15;

  const int bm0 = blockIdx.y * BM;
  const int bn0 = blockIdx.x * BN;

  // staging: 1024 16B-chunks per matrix per tile; thread covers idx = j*512 + tid.
  // row = idx>>2, global chunk = (idx&3) ^ ((row>>1)&3) = (idx&3) ^ ((idx>>3)&3).
  const signed char* gA[2];
  const signed char* gB[2];
#pragma unroll
  for (int j = 0; j < 2; ++j) {
    const int idx = j * 512 + tid;
    const int row = idx >> 2;
    const int gch = (idx & 3) ^ ((idx >> 3) & 3);
    gA[j] = A + (size_t)(bm0 + row) * K + gch * 16;
    gB[j] = B + (size_t)(bn0 + row) * K + gch * 16;
  }
  const int ldsbase = wave * 64 * 16;  // wave-uniform; HW adds lane*16

#define STAGE(slot)                                  \
  do {                                               \
    signed char* la = &lds[slot][0][ldsbase];        \
    signed char* lb = &lds[slot][1][ldsbase];        \
    GLOAD_LDS(gA[0], la);                            \
    GLOAD_LDS(gA[1], la + 8192);                     \
    GLOAD_LDS(gB[0], lb);                            \
    GLOAD_LDS(gB[1], lb + 8192);                     \
    gA[0] += BKB; gA[1] += BKB;                      \
    gB[0] += BKB; gB[1] += BKB;                      \
  } while (0)

  // fragment: row = wm*128 + mt*16 + l16, swizzled 16B k-chunk. 2-way banks = free.
  const int kchunk = quad ^ ((l16 >> 1) & 3);
  const int aoff = (wm * 128 + l16) * BKB + kchunk * 16;
  const int boff = (wn * 64 + l16) * BKB + kchunk * 16;
  // mt/nt tile stride: 16 rows * 64 B = 1024 B = 64 v4i

  v4i acc[8][4] = {};

  STAGE(0);
  STAGE(1);
  STAGE(2);
  asm volatile("s_waitcnt vmcnt(8)" ::: "memory");  // tile 0 landed; t1,t2 in flight
  asm volatile("s_barrier" ::: "memory");

  const int NT = K / BKB;  // 64
  for (int t = 0; t < NT; ++t) {
    if (t + 3 < NT) STAGE((t + 3) & 3);
    const int slot = t & 3;
    const v4i* fA = (const v4i*)&lds[slot][0][aoff];
    const v4i* fB = (const v4i*)&lds[slot][1][boff];
    v4i af[8], bf[4];
#pragma unroll
    for (int i = 0; i < 8; ++i) af[i] = fA[i * 64];
#pragma unroll
    for (int i = 0; i < 4; ++i) bf[i] = fB[i * 64];
    __builtin_amdgcn_s_setprio(1);
#pragma unroll
    for (int mt = 0; mt < 8; ++mt)
#pragma unroll
      for (int nt = 0; nt < 4; ++nt)
        acc[mt][nt] = __builtin_amdgcn_mfma_i32_16x16x64_i8(
            af[mt], bf[nt], acc[mt][nt], 0, 0, 0);
    __builtin_amdgcn_s_setprio(0);
    // tile t+1 fully landed (only t+2,t+3 = 8 loads may remain in flight)
    asm volatile("s_waitcnt vmcnt(8)" ::: "memory");
    asm volatile("s_barrier" ::: "memory");
  }
#undef STAGE

  // epilogue: D layout col=lane&15, row=quad*4+reg (shape-determined, dtype-indep)
  const float ws = *wsc;
#pragma unroll
  for (int mt = 0; mt < 8; ++mt) {
    const int row = bm0 + wm * 128 + mt * 16 + quad * 4;
    float sc[4];
#pragma unroll
    for (int r = 0; r < 4; ++r) sc[r] = ws * sx[row + r];
#pragma unroll
    for (int nt = 0; nt < 4; ++nt) {
      const int col = bn0 + wn * 64 + nt * 16 + l16;
      const float bias = bt[col];
#pragma unroll
      for (int r = 0; r < 4; ++r)
        C[(size_t)(row + r) * N + col] = sc[r] * (float)acc[mt][nt][r] + bias;
    }
  }
}

// ---------- launch ----------

extern "C" void kernel_launch(void* const* d_in, const int* in_sizes, int n_in,
                              void* d_out, int out_size, void* d_ws, size_t ws_size,
                              hipStream_t stream) {
  const float* x = (const float*)d_in[0];
  const float* W = (const float*)d_in[1];
  const float* w_scale = (const float*)d_in[2];
  const float* b = (const float*)d_in[3];
  const float* b_scale = (const float*)d_in[4];
  float* out = (float*)d_out;

  const int K = 4096;             // D_IN
  const int N = in_sizes[3];      // D_OUT = 4096
  const int M = in_sizes[0] / K;  // B*S = 8192

  // workspace layout
  char* ws = (char*)d_ws;
  signed char* xb = (signed char*)ws;                        // M*K i8 (32 MB)
  signed char* Tw = (signed char*)(ws + (size_t)M * K);      // N*K i8 (16 MB)
  float* bt = (float*)(ws + (size_t)M * K + (size_t)N * K);  // N fp32
  float* sx = bt + N;                                        // M fp32
  unsigned* mx = (unsigned*)(sx + M);                        // [0]=max|W|,[1]=max|b|

  hipMemsetAsync(mx, 0, 8, stream);

  const long nW4 = (long)N * K / 4;
  const int nb4 = N / 4;

  absmax2_kernel<<<1025, 256, 0, stream>>>((const float4*)W, nW4,
                                           (const float4*)b, nb4, mx);

  xquant_kernel<<<M, 256, 0, stream>>>((const float4*)x, xb, sx, K);

  prep_w_kernel<<<8193, 256, 0, stream>>>((const float4*)W, nW4,
                                          (const float4*)b, nb4, mx, b_scale,
                                          (int*)Tw, (float4*)bt);

  dim3 gg(N / BN, M / BM);
  gemm_tern_i8<<<gg, 512, 0, stream>>>(xb, Tw, sx, bt, w_scale, out, M, N, K);
}

// Round 2
// 406.651 us; speedup vs baseline: 1.1857x; 1.0062x over previous
//
#include <hip/hip_runtime.h>

typedef int v4i __attribute__((ext_vector_type(4)));

#define BM 256
#define BN 256
#define BKB 64   // K-bytes per ring slot (i8 elems). 64 B rows.
#define NRING 4  // 4 slots x (16KB A + 16KB B) = 128 KB LDS, prefetch distance 3

// async global->LDS, 16B per lane. LDS dest = wave-uniform base + lane*16.
#define GLOAD_LDS(gptr, lptr)                                                         \
  __builtin_amdgcn_global_load_lds(                                                   \
      (const __attribute__((address_space(1))) unsigned int*)(gptr),                  \
      (__attribute__((address_space(3))) unsigned int*)(lptr), 16, 0, 0)

// ---------- preprocessing ----------

__device__ __forceinline__ float max4abs(float4 v) {
  return fmaxf(fmaxf(fabsf(v.x), fabsf(v.y)), fmaxf(fabsf(v.z), fabsf(v.w)));
}

__device__ __forceinline__ int packq4(float4 v, float inv) {
  int b0 = ((int)fminf(127.f, fmaxf(-127.f, rintf(v.x * inv)))) & 255;
  int b1 = ((int)fminf(127.f, fmaxf(-127.f, rintf(v.y * inv)))) & 255;
  int b2 = ((int)fminf(127.f, fmaxf(-127.f, rintf(v.z * inv)))) & 255;
  int b3 = ((int)fminf(127.f, fmaxf(-127.f, rintf(v.w * inv)))) & 255;
  return b0 | (b1 << 8) | (b2 << 16) | (b3 << 24);
}

// Fused: blocks [0,nrows) per-row i8-quantize x; blocks [nrows,nrows+1024) reduce
// max|W|; last block reduces max|b|. All independent -> one dispatch.
__global__ void prep1_kernel(const float4* __restrict__ X4,
                             signed char* __restrict__ Q,
                             float* __restrict__ sx, int K, int nrows,
                             const float4* __restrict__ W4, long nW4,
                             const float4* __restrict__ b4, int nb4,
                             unsigned* __restrict__ mx) {
  __shared__ float sm[4];
  const int tid = threadIdx.x;
  const int bid = blockIdx.x;

  if (bid < nrows) {  // ---- xquant: one block per row, K==4096 assumed
    const float4* xr = X4 + (size_t)bid * (K / 4);
    float4 v0 = xr[tid], v1 = xr[tid + 256], v2 = xr[tid + 512], v3 = xr[tid + 768];
    float m = fmaxf(fmaxf(max4abs(v0), max4abs(v1)), fmaxf(max4abs(v2), max4abs(v3)));
    for (int off = 32; off > 0; off >>= 1) m = fmaxf(m, __shfl_down(m, off));
    if ((tid & 63) == 0) sm[tid >> 6] = m;
    __syncthreads();
    const float total = fmaxf(fmaxf(sm[0], sm[1]), fmaxf(sm[2], sm[3]));
    const float inv = 127.f / total;
    int* qw = (int*)(Q + (size_t)bid * K);
    qw[tid]       = packq4(v0, inv);
    qw[tid + 256] = packq4(v1, inv);
    qw[tid + 512] = packq4(v2, inv);
    qw[tid + 768] = packq4(v3, inv);
    if (tid == 0) sx[bid] = total * (1.f / 127.f);
    return;
  }

  // ---- absmax reductions
  float m = 0.f;
  const bool isB = (bid == gridDim.x - 1);
  if (!isB) {
    const long wb = bid - nrows;           // 0..1023
    const long stride = 1024L * blockDim.x;
    for (long i = wb * blockDim.x + tid; i < nW4; i += stride)
      m = fmaxf(m, max4abs(W4[i]));
  } else {
    for (int i = tid; i < nb4; i += blockDim.x) m = fmaxf(m, max4abs(b4[i]));
  }
  for (int off = 32; off > 0; off >>= 1) m = fmaxf(m, __shfl_down(m, off));
  if ((tid & 63) == 0) sm[tid >> 6] = m;
  __syncthreads();
  if (tid == 0) {
    m = fmaxf(fmaxf(sm[0], sm[1]), fmaxf(sm[2], sm[3]));
    atomicMax(mx + (isB ? 1 : 0), __float_as_uint(m));  // nonneg: uint order == float
  }
}

// Ternarize W -> i8{-1,0,1} (4 packed dwords per thread per iter, coalesced);
// last block ternarizes b -> fp32.
__global__ void prep_w_kernel(const float4* __restrict__ W4, long nW4,
                              const float4* __restrict__ b4, int nb4,
                              const unsigned* __restrict__ mx,
                              const float* __restrict__ bscale,
                              int* __restrict__ Twi, float4* __restrict__ bt) {
  if (blockIdx.x == gridDim.x - 1) {  // bias block
    const float delta = 0.05f * __uint_as_float(mx[1]);
    const float s = *bscale;
    for (int i = threadIdx.x; i < nb4; i += blockDim.x) {
      float4 v = b4[i];
      float4 o;
      o.x = v.x > delta ? s : (v.x < -delta ? -s : 0.f);
      o.y = v.y > delta ? s : (v.y < -delta ? -s : 0.f);
      o.z = v.z > delta ? s : (v.z < -delta ? -s : 0.f);
      o.w = v.w > delta ? s : (v.w < -delta ? -s : 0.f);
      bt[i] = o;
    }
    return;
  }
  const float delta = 0.05f * __uint_as_float(mx[0]);
  const long stride = (long)(gridDim.x - 1) * blockDim.x;
  for (long i = blockIdx.x * (long)blockDim.x + threadIdx.x; i < nW4; i += stride) {
    float4 w = W4[i];
    int b0 = w.x > delta ? 1 : (w.x < -delta ? 0xFF : 0);
    int b1 = w.y > delta ? 1 : (w.y < -delta ? 0xFF : 0);
    int b2 = w.z > delta ? 1 : (w.z < -delta ? 0xFF : 0);
    int b3 = w.w > delta ? 1 : (w.w < -delta ? 0xFF : 0);
    Twi[i] = b0 | (b1 << 8) | (b2 << 16) | (b3 << 24);
  }
}

// ---------- GEMM: C[m,n] = ws*sx[m]*(sum_k Aq[m,k]*T[n,k]) + bt[n], exact i32 acc ----
// 256x256 tile, 8 waves (2Mx4N), wave tile 128x64, 4x4-slot ring, prefetch dist 3,
// counted vmcnt(8) (never 0 in loop). NEW: 4-phase cadence per K-step (8-phase
// template port): each phase {ds_read subtile, stage half-tile, barrier,
// lgkmcnt(0), setprio(1), 8 MFMA, setprio(0), barrier}. Phase reads: 6/2/4/0
// ds_read_b128; stages: ph0=A-half, ph1=B-half; vmcnt(8) in ph3.
// Fragment layout + XOR chunk swizzle byte-identical to the verified version.
__global__ __launch_bounds__(512, 2) void gemm_tern_i8(
    const signed char* __restrict__ A,   // [M,K] i8 quantized x
    const signed char* __restrict__ B,   // [N,K] i8 ternary {-1,0,1}
    const float* __restrict__ sx,        // [M] per-row x scale
    const float* __restrict__ bt,        // [N]
    const float* __restrict__ wsc,       // scalar
    float* __restrict__ C,               // [M,N] fp32
    int M, int N, int K) {
  __shared__ __align__(16) signed char lds[NRING][2][BM * BKB];  // 128 KB

  const int tid = threadIdx.x;
  const int wave = tid >> 6;
  const int lane = tid & 63;
  const int wm = wave >> 2, wn = wave & 3;  // 2 x 4 wave grid
  const int quad = lane >> 4;               // 0..3
  const int l16 = lane & 15;

  // XCD-aware bijective swizzle: 512 wgs, 8 XCDs -> 64 wgs each = a 4-M-row band,
  // column-major inside the band (concurrent set ~ 4 A-panels + 8 B-panels).
  const unsigned orig = blockIdx.x;
  const unsigned xcd = orig & 7;
  const unsigned r8 = orig >> 3;            // 0..63
  const int by = (int)(xcd * 4 + (r8 & 3)); // 0..31  (M)
  const int bx = (int)(r8 >> 2);            // 0..15  (N)
  const int bm0 = by * BM;
  const int bn0 = bx * BN;

  // staging: 1024 16B-chunks per matrix per tile; thread covers idx = j*512 + tid.
  // row = idx>>2, global chunk = (idx&3) ^ ((row>>1)&3) = (idx&3) ^ ((idx>>3)&3).
  const signed char* gA[2];
  const signed char* gB[2];
#pragma unroll
  for (int j = 0; j < 2; ++j) {
    const int idx = j * 512 + tid;
    const int row = idx >> 2;
    const int gch = (idx & 3) ^ ((idx >> 3) & 3);
    gA[j] = A + (size_t)(bm0 + row) * K + gch * 16;
    gB[j] = B + (size_t)(bn0 + row) * K + gch * 16;
  }
  const int ldsbase = wave * 64 * 16;  // wave-uniform; HW adds lane*16

#define STAGE_A(slot)                                \
  do {                                               \
    signed char* la = &lds[slot][0][ldsbase];        \
    GLOAD_LDS(gA[0], la);                            \
    GLOAD_LDS(gA[1], la + 8192);                     \
    gA[0] += BKB; gA[1] += BKB;                      \
  } while (0)
#define STAGE_B(slot)                                \
  do {                                               \
    signed char* lb = &lds[slot][1][ldsbase];        \
    GLOAD_LDS(gB[0], lb);                            \
    GLOAD_LDS(gB[1], lb + 8192);                     \
    gB[0] += BKB; gB[1] += BKB;                      \
  } while (0)

#define BAR()  do { __builtin_amdgcn_sched_barrier(0); __builtin_amdgcn_s_barrier(); \
                    __builtin_amdgcn_sched_barrier(0); } while (0)
#define WAITLGKM() do { asm volatile("s_waitcnt lgkmcnt(0)" ::: "memory");           \
                        __builtin_amdgcn_sched_barrier(0); } while (0)

  // fragment: row = wm*128 + mt*16 + l16, swizzled 16B k-chunk. 2-way banks = free.
  const int kchunk = quad ^ ((l16 >> 1) & 3);
  const int aoff = (wm * 128 + l16) * BKB + kchunk * 16;
  const int boff = (wn * 64 + l16) * BKB + kchunk * 16;
  // mt/nt tile stride: 16 rows * 64 B = 1024 B = 64 v4i

  v4i acc[8][4] = {};

  STAGE_A(0); STAGE_B(0);
  STAGE_A(1); STAGE_B(1);
  STAGE_A(2); STAGE_B(2);
  asm volatile("s_waitcnt vmcnt(8)" ::: "memory");  // tile 0 landed; t1,t2 in flight
  BAR();

  const int NT = K / BKB;  // 64
  for (int t = 0; t < NT; ++t) {
    const int slot = t & 3;
    const v4i* fA = (const v4i*)&lds[slot][0][aoff];
    const v4i* fB = (const v4i*)&lds[slot][1][boff];
    const bool pf = (t + 3 < NT);
    const int pslot = (t + 3) & 3;
    v4i af[8], bf[4];

    // ---- phase 0: mt0-3 x nt0-1 (reads 6, stage A)
    af[0] = fA[0]; af[1] = fA[64]; af[2] = fA[128]; af[3] = fA[192];
    bf[0] = fB[0]; bf[1] = fB[64];
    if (pf) STAGE_A(pslot);
    BAR();
    WAITLGKM();
    __builtin_amdgcn_s_setprio(1);
#pragma unroll
    for (int mt = 0; mt < 4; ++mt)
#pragma unroll
      for (int nt = 0; nt < 2; ++nt)
        acc[mt][nt] = __builtin_amdgcn_mfma_i32_16x16x64_i8(af[mt], bf[nt], acc[mt][nt], 0, 0, 0);
    __builtin_amdgcn_s_setprio(0);
    BAR();

    // ---- phase 1: mt0-3 x nt2-3 (reads 2, stage B)
    bf[2] = fB[128]; bf[3] = fB[192];
    if (pf) STAGE_B(pslot);
    BAR();
    WAITLGKM();
    __builtin_amdgcn_s_setprio(1);
#pragma unroll
    for (int mt = 0; mt < 4; ++mt)
#pragma unroll
      for (int nt = 2; nt < 4; ++nt)
        acc[mt][nt] = __builtin_amdgcn_mfma_i32_16x16x64_i8(af[mt], bf[nt], acc[mt][nt], 0, 0, 0);
    __builtin_amdgcn_s_setprio(0);
    BAR();

    // ---- phase 2: mt4-7 x nt2-3 (reads 4)
    af[4] = fA[256]; af[5] = fA[320]; af[6] = fA[384]; af[7] = fA[448];
    BAR();
    WAITLGKM();
    __builtin_amdgcn_s_setprio(1);
#pragma unroll
    for (int mt = 4; mt < 8; ++mt)
#pragma unroll
      for (int nt = 2; nt < 4; ++nt)
        acc[mt][nt] = __builtin_amdgcn_mfma_i32_16x16x64_i8(af[mt], bf[nt], acc[mt][nt], 0, 0, 0);
    __builtin_amdgcn_s_setprio(0);
    BAR();

    // ---- phase 3: mt4-7 x nt0-1 (no reads; counted vmcnt -> slot t+1 ready)
    asm volatile("s_waitcnt vmcnt(8)" ::: "memory");
    BAR();
    __builtin_amdgcn_s_setprio(1);
#pragma unroll
    for (int mt = 4; mt < 8; ++mt)
#pragma unroll
      for (int nt = 0; nt < 2; ++nt)
        acc[mt][nt] = __builtin_amdgcn_mfma_i32_16x16x64_i8(af[mt], bf[nt], acc[mt][nt], 0, 0, 0);
    __builtin_amdgcn_s_setprio(0);
    BAR();
  }
#undef STAGE_A
#undef STAGE_B
#undef BAR
#undef WAITLGKM

  // epilogue: D layout col=lane&15, row=quad*4+reg (shape-determined, dtype-indep)
  const float ws = *wsc;
#pragma unroll
  for (int mt = 0; mt < 8; ++mt) {
    const int row = bm0 + wm * 128 + mt * 16 + quad * 4;
    float sc[4];
#pragma unroll
    for (int r = 0; r < 4; ++r) sc[r] = ws * sx[row + r];
#pragma unroll
    for (int nt = 0; nt < 4; ++nt) {
      const int col = bn0 + wn * 64 + nt * 16 + l16;
      const float bias = bt[col];
#pragma unroll
      for (int r = 0; r < 4; ++r)
        C[(size_t)(row + r) * N + col] = sc[r] * (float)acc[mt][nt][r] + bias;
    }
  }
}

// ---------- launch ----------

extern "C" void kernel_launch(void* const* d_in, const int* in_sizes, int n_in,
                              void* d_out, int out_size, void* d_ws, size_t ws_size,
                              hipStream_t stream) {
  const float* x = (const float*)d_in[0];
  const float* W = (const float*)d_in[1];
  const float* w_scale = (const float*)d_in[2];
  const float* b = (const float*)d_in[3];
  const float* b_scale = (const float*)d_in[4];
  float* out = (float*)d_out;

  const int K = 4096;             // D_IN
  const int N = in_sizes[3];      // D_OUT = 4096
  const int M = in_sizes[0] / K;  // B*S = 8192

  // workspace layout
  char* ws = (char*)d_ws;
  signed char* xb = (signed char*)ws;                        // M*K i8 (32 MB)
  signed char* Tw = (signed char*)(ws + (size_t)M * K);      // N*K i8 (16 MB)
  float* bt = (float*)(ws + (size_t)M * K + (size_t)N * K);  // N fp32
  float* sx = bt + N;                                        // M fp32
  unsigned* mx = (unsigned*)(sx + M);                        // [0]=max|W|,[1]=max|b|

  hipMemsetAsync(mx, 0, 8, stream);

  const long nW4 = (long)N * K / 4;
  const int nb4 = N / 4;

  // fused xquant + absmax(W) + absmax(b): 8192 + 1024 + 1 blocks
  prep1_kernel<<<M + 1024 + 1, 256, 0, stream>>>((const float4*)x, xb, sx, K, M,
                                                 (const float4*)W, nW4,
                                                 (const float4*)b, nb4, mx);

  prep_w_kernel<<<2049, 256, 0, stream>>>((const float4*)W, nW4,
                                          (const float4*)b, nb4, mx, b_scale,
                                          (int*)Tw, (float4*)bt);

  const int nwg = (N / BN) * (M / BM);  // 512, divisible by 8
  gemm_tern_i8<<<nwg, 512, 0, stream>>>(xb, Tw, sx, bt, w_scale, out, M, N, K);
}